// Round 1
// baseline (129.120 us; speedup 1.0000x reference)
//
#include <hip/hip_runtime.h>

#define SM 1028
#define D_ 256
#define S_ 1024
#define B_ 8

// Kernel 1: c[b,d,i] = sum_{w<i} x[b,d,w] * weight[d,i,w]; y = x*(1+relu(c))
// grid: 4096 blocks = 256 d * 16 row-groups (64 rows each), heavy groups first.
// block: 256 threads = 4 waves; each wave -> 4 groups of 16 lanes; each group
// owns 4 consecutive rows; lanes tile w in 64-wide chunks (float4 per lane).
__global__ __launch_bounds__(256, 4)
void lie_mix_kernel(const float* __restrict__ x, const float* __restrict__ weight,
                    float* __restrict__ y) {
  int bid = blockIdx.x;
  int d = bid & 255;
  int bi = 15 - (bid >> 8);   // heavy (large i0) blocks get low blockIdx
  int i0 = bi << 6;           // block rows: [i0, i0+64)

  __shared__ float xs[B_][S_];

  int t = threadIdx.x;
  // stage x[b][d][0 .. i0+64) into LDS (float4, coalesced)
  int wlim4 = (i0 + 64) >> 2;
  for (int bb = 0; bb < B_; ++bb) {
    const float4* src = (const float4*)(x + ((size_t)bb * D_ + d) * S_);
    float4* dst = (float4*)(&xs[bb][0]);
    for (int idx = t; idx < wlim4; idx += 256) dst[idx] = src[idx];
  }
  __syncthreads();

  int lane = t & 63;
  int wid = t >> 6;
  int g = lane >> 4;          // 16-lane group within wave
  int jj = lane & 15;         // lane within group
  int rbase = i0 + wid * 16 + g * 4;   // this group's 4 rows

  const float* wbase = weight + ((size_t)d * SM + rbase) * SM + 4 * jj;

  float acc[4][8];
#pragma unroll
  for (int k = 0; k < 4; ++k)
#pragma unroll
    for (int b = 0; b < 8; ++b) acc[k][b] = 0.f;

  int F = i0 >> 6;  // number of fully-valid (unmasked) 64-wide chunks

  float4 wc[4];
#pragma unroll
  for (int k = 0; k < 4; ++k) wc[k] = *(const float4*)(wbase + (size_t)k * SM);

  for (int c = 0; c < F; ++c) {
    float4 wn[4];
    const float* p = wbase + (c + 1) * 64;
#pragma unroll
    for (int k = 0; k < 4; ++k) wn[k] = *(const float4*)(p + (size_t)k * SM);
    int w0 = c * 64;
#pragma unroll
    for (int b = 0; b < 8; ++b) {
      float4 xb = *(const float4*)&xs[b][w0 + 4 * jj];
#pragma unroll
      for (int k = 0; k < 4; ++k) {
        acc[k][b] += xb.x * wc[k].x;
        acc[k][b] += xb.y * wc[k].y;
        acc[k][b] += xb.z * wc[k].z;
        acc[k][b] += xb.w * wc[k].w;
      }
    }
#pragma unroll
    for (int k = 0; k < 4; ++k) wc[k] = wn[k];
  }

  // final masked chunk c == F (w in [i0, i0+64)): element w valid iff w < row
  {
    int lim_base = wid * 16 + g * 4;  // rbase - i0
    float4 wm[4];
#pragma unroll
    for (int k = 0; k < 4; ++k) {
      int lim = lim_base + k;
      wm[k].x = (4 * jj + 0 < lim) ? wc[k].x : 0.f;
      wm[k].y = (4 * jj + 1 < lim) ? wc[k].y : 0.f;
      wm[k].z = (4 * jj + 2 < lim) ? wc[k].z : 0.f;
      wm[k].w = (4 * jj + 3 < lim) ? wc[k].w : 0.f;
    }
#pragma unroll
    for (int b = 0; b < 8; ++b) {
      float4 xb = *(const float4*)&xs[b][i0 + 4 * jj];
#pragma unroll
      for (int k = 0; k < 4; ++k) {
        acc[k][b] += xb.x * wm[k].x;
        acc[k][b] += xb.y * wm[k].y;
        acc[k][b] += xb.z * wm[k].z;
        acc[k][b] += xb.w * wm[k].w;
      }
    }
  }

  // reduce across the 16 lanes of the group (xor masks 1,2,4,8 stay in-group)
#pragma unroll
  for (int s = 1; s < 16; s <<= 1) {
#pragma unroll
    for (int k = 0; k < 4; ++k)
#pragma unroll
      for (int b = 0; b < 8; ++b)
        acc[k][b] += __shfl_xor(acc[k][b], s, 64);
  }

  // lanes jj=0..7 each write batch b=jj for the group's 4 rows
  if (jj < 8) {
#pragma unroll
    for (int k = 0; k < 4; ++k) {
      float v = acc[k][0];
#pragma unroll
      for (int b = 1; b < 8; ++b) v = (jj == b) ? acc[k][b] : v;
      float r = fmaxf(v, 0.f);
      float xv = xs[jj][rbase + k];
      y[((size_t)jj * D_ + d) * S_ + rbase + k] = xv * (1.f + r);
    }
  }
}

// Kernel 2: LayerNorm over channel axis d (size 256) per (b, s).
// grid: 256 blocks = 8 b * 32 s-chunks (32 positions each).
__global__ __launch_bounds__(256)
void ln_kernel(const float* __restrict__ y, const float* __restrict__ gamma,
               const float* __restrict__ beta, float* __restrict__ out) {
  __shared__ float tile[D_][33];
  __shared__ float ps[8][32];
  __shared__ float pq[8][32];
  __shared__ float mu[32];
  __shared__ float rs[32];
  int b = blockIdx.x >> 5;
  int s0 = (blockIdx.x & 31) << 5;
  int t = threadIdx.x;
  int sj = t & 31, dq = t >> 5;
  for (int dd = dq; dd < D_; dd += 8)
    tile[dd][sj] = y[((size_t)b * D_ + dd) * S_ + s0 + sj];
  __syncthreads();
  float sm = 0.f, sq = 0.f;
#pragma unroll 8
  for (int r = 0; r < 32; ++r) {
    float v = tile[dq * 32 + r][sj];
    sm += v;
    sq += v * v;
  }
  ps[dq][sj] = sm;
  pq[dq][sj] = sq;
  __syncthreads();
  if (t < 32) {
    float S = 0.f, Q = 0.f;
#pragma unroll
    for (int q = 0; q < 8; ++q) { S += ps[q][t]; Q += pq[q][t]; }
    float m = S * (1.f / 256.f);
    float var = Q * (1.f / 256.f) - m * m;
    mu[t] = m;
    rs[t] = rsqrtf(var + 1e-5f);
  }
  __syncthreads();
  for (int dd = dq; dd < D_; dd += 8) {
    float v = tile[dd][sj];
    out[((size_t)b * D_ + dd) * S_ + s0 + sj] =
        (v - mu[sj]) * rs[sj] * gamma[dd] + beta[dd];
  }
}

extern "C" void kernel_launch(void* const* d_in, const int* in_sizes, int n_in,
                              void* d_out, int out_size, void* d_ws, size_t ws_size,
                              hipStream_t stream) {
  const float* x = (const float*)d_in[0];
  const float* weight = (const float*)d_in[1];
  const float* gamma = (const float*)d_in[2];
  const float* beta = (const float*)d_in[3];
  float* out = (float*)d_out;
  float* y = (float*)d_ws;  // 8*256*1024 f32 = 8 MB scratch

  lie_mix_kernel<<<4096, 256, 0, stream>>>(x, weight, y);
  ln_kernel<<<256, 256, 0, stream>>>(y, gamma, beta, out);
}